// Round 18
// baseline (69.275 us; speedup 1.0000x reference)
//
#include <hip/hip_runtime.h>
#include <math.h>

#define Cc 512
#define Pp 1024
#define NROW 25088      // B*N = 8*3136
#define BM 128          // rows per block
#define BNP 256         // centroid cols per block (4 pblocks)
#define NMB 196         // real mblocks = 25088/128
#define NMB_PAD 200     // padded so mblocks group 8-per-XCD
#define BIAS 4096.f     // makes v = cn+BIAS-2dot strictly positive for packing

typedef short  bf16x8 __attribute__((ext_vector_type(8)));   // 8 bf16 = 4 VGPR
typedef float  f32x4  __attribute__((ext_vector_type(4)));
typedef unsigned short u16x8 __attribute__((ext_vector_type(8)));
typedef unsigned short u16x4 __attribute__((ext_vector_type(4)));

__device__ __forceinline__ unsigned short bf16_rne(float f) {
    unsigned int u = __float_as_uint(f);
    return (unsigned short)((u + 0x7fffu + ((u >> 16) & 1u)) >> 16);
}

// branch-free sorted insert (float), for cross-pblock merges
#define TOP3_INSERT(t0, t1, t2, v)                                  \
    do {                                                            \
        float _n0 = fminf((t0), (v));                               \
        float _h0 = fmaxf((t0), (v));                               \
        float _n1 = fminf((t1), _h0);                               \
        float _h1 = fmaxf((t1), _h0);                               \
        float _n2 = fminf((t2), _h1);                               \
        (t0) = _n0; (t1) = _n1; (t2) = _n2;                         \
    } while (0)

// branch-free sorted insert (packed u32: high-24 float bits | 8-bit col id)
#define TOP3_INS_U32(t0, t1, t2, v)                                 \
    do {                                                            \
        unsigned int _n0 = min((t0), (v));                          \
        unsigned int _h0 = max((t0), (v));                          \
        unsigned int _n1 = min((t1), _h0);                          \
        unsigned int _h1 = max((t1), _h0);                          \
        unsigned int _n2 = min((t2), _h1);                          \
        (t0) = _n0; (t1) = _n1; (t2) = _n2;                         \
    } while (0)

#define GLOAD_LDS16(gp, lp)                                             \
    __builtin_amdgcn_global_load_lds(                                   \
        (const __attribute__((address_space(1))) void*)(const void*)(gp),\
        (__attribute__((address_space(3))) void*)(void*)(lp), 16, 0, 0)

// ---------------------------------------------------------------------------
// Fused transpose-conv (proven): fp32 -> bf16 RNE, re-tiled into MFMA
// fragment order, fused row squared-norm. Blocks 0..783 embeds, 784..815
// centroids. Tile = 16 rows x 32 k = 64 chunks of 16B; chunk (g,q) at lane
// l = g*16+q. Tile id = rowblk_base + kt*kts + nrt,
// rowblk_base = rb + (rb>>lg)*(15<<lg).
// ---------------------------------------------------------------------------
__global__ __launch_bounds__(256) void tconv_fused_kernel(
        const float* __restrict__ embeds, const float* __restrict__ cents,
        unsigned short* __restrict__ EbT, unsigned short* __restrict__ CbT,
        float* __restrict__ fnorm, float* __restrict__ cnorm) {
    __shared__ unsigned short buf[32 * 512];   // 32 KB
    __shared__ float snorm[32 * 8];            // 1 KB

    const int bid = blockIdx.x;
    const bool isE = bid < (NROW / 32);
    const float*    src = isE ? embeds : cents;
    unsigned short* dst = isE ? EbT : CbT;
    float*          nrm = isE ? fnorm : cnorm;
    const int       lg  = isE ? 3 : 6;
    const int       kts = isE ? 8 : 64;
    const size_t R0 = (size_t)(isE ? bid : bid - NROW / 32) * 32;

    const int t = threadIdx.x;

    #pragma unroll
    for (int p = 0; p < 16; ++p) {
        int idx = p * 1024 + t * 4;
        float4 v = *(const float4*)(src + R0 * Cc + idx);
        u16x4 o;
        o[0] = bf16_rne(v.x); o[1] = bf16_rne(v.y);
        o[2] = bf16_rne(v.z); o[3] = bf16_rne(v.w);
        *(u16x4*)&buf[idx] = o;
    }
    __syncthreads();

    const int w = t >> 6, g = (t >> 4) & 3, q = t & 15, l = t & 63;
    const int rb = (int)(R0 >> 4);
    const int rowblk_base = rb + (rb >> lg) * (15 << lg);
    float fns = 0.f;
    #pragma unroll
    for (int p = 0; p < 8; ++p) {
        int cg  = p * 4 + w;              // tile-local group 0..31
        int kt  = cg >> 1, nrt = cg & 1;
        int row = nrt * 16 + q;
        u16x8 ch = *(const u16x8*)&buf[row * 512 + kt * 32 + g * 8];
        #pragma unroll
        for (int i = 0; i < 8; ++i) {
            float x = __uint_as_float((unsigned int)(unsigned short)ch[i] << 16);
            fns = fmaf(x, x, fns);
        }
        size_t tile = (size_t)rowblk_base + (size_t)kt * kts + nrt;
        *(u16x8*)(dst + tile * 512 + l * 8) = ch;
    }
    snorm[((w & 1) * 16 + q) * 8 + (w >> 1) * 4 + g] = fns;
    __syncthreads();
    if (t < 32) {
        float s = 0.f;
        #pragma unroll
        for (int j = 0; j < 8; ++j) s += snorm[t * 8 + j];
        nrm[R0 + t] = s;
    }
}

// ---------------------------------------------------------------------------
// Main (R12 pipeline, BNP widened to 256 to HALVE A L2-traffic): 128x256
// tile, 4 pblocks (was 8). Wave tile 64x128: acc[8][4] = 128 AGPR; af
// double-buffered 64 VGPR; bc read 4-at-a-time (caps arch VGPR; total
// unified ~250 <= 256 band -> same 2 waves/SIMD as R12, half the traffic,
// 64 MFMA/wave between barriers). A direct global->VGPR; B 2x32KB dbuf via
// gload_lds (8 DMA/thread/iter); counted vmcnt(8) per iter (never 0 until
// tail). Fragment-ordered reads: contiguous 1KB/wave => conflict-free.
// Swapped-operand MFMA (cents lane-local in C) + packed-u32 top-3.
// Grid: 800 blocks (200 padded mblocks x 4 pblocks), 256 thr = 4 waves 2x2.
// acc[mc][nr]: cent = p0+wn*128+mc*16+g*4+reg ; row = row0+wm*64+nr*16+q
// ---------------------------------------------------------------------------
__global__ __launch_bounds__(256) void mfma_topk_kernel(
        const unsigned short* __restrict__ EbT, const unsigned short* __restrict__ CbT,
        const float* __restrict__ cnorm, float* __restrict__ wsTop) {
    const int xcd = blockIdx.x & 7;
    const int t4  = blockIdx.x >> 3;          // 0..99
    const int mblock = ((t4 >> 2) << 3) | xcd;
    const int pblock = t4 & 3;
    if (mblock >= NMB) return;                // uniform early-exit

    __shared__ unsigned short Blds[2][16384]; // 2 x 32 KB (2 k-panels each)
    __shared__ float tops[2][BM][3];          // 3 KB

    const int tid  = threadIdx.x;
    const int lane = tid & 63;
    const int w    = tid >> 6;
    const int wm   = w >> 1;       // 0..1 row half
    const int wn   = w & 1;        // 0..1 cent half (128 cents each)
    const int g    = lane >> 4;    // 0..3
    const int q    = lane & 15;    // 0..15
    const int row0 = mblock * BM;
    const int p0   = pblock * BNP;

    f32x4 acc[8][4];               // [mc][nr] = 128 AGPR
    #pragma unroll
    for (int mc = 0; mc < 8; ++mc)
        #pragma unroll
        for (int nr = 0; nr < 4; ++nr) acc[mc][nr] = (f32x4){0.f, 0.f, 0.f, 0.f};

    // A fragment base (u16): tile=512 u16, tiles [mblock][kt 16][nrt 8]
    const unsigned short* Ab = EbT + ((size_t)mblock * 128 + wm * 4) * 512 + lane * 8;
    // B: tiles [kt 16][ptile 64]; pblock covers ptiles [p*16, p*16+16),
    // contiguous within each kt (16 KB per k-panel for this block)
    const unsigned short* Bg = CbT + (size_t)pblock * 16 * 512;

    // stage TWO k-panels (kt = 2i, 2i+1): 16 KB each, 8 DMA instrs/thread
    auto STAGE_B2 = [&](int buf, int i) {
        #pragma unroll
        for (int ks = 0; ks < 2; ++ks) {
            const unsigned short* src = Bg + (size_t)(2 * i + ks) * 32768;
            #pragma unroll
            for (int it = 0; it < 4; ++it) {
                int c = tid + it * 256;       // 0..1023 chunks of 16B
                GLOAD_LDS16(src + c * 8,
                            (char*)Blds[buf] + ks * 16384 + c * 16);
            }
        }
    };

    bf16x8 af[2][2][4];            // [buf][ks][nr] = 64 VGPR
    // prologue: B panel-pair 0 (8 DMA, oldest), A iter0 (8 loads)
    STAGE_B2(0, 0);
    #pragma unroll
    for (int ks = 0; ks < 2; ++ks)
        #pragma unroll
        for (int nr = 0; nr < 4; ++nr)
            af[0][ks][nr] = *(const bf16x8*)(Ab + (size_t)ks * 4096 + nr * 512);
    // outstanding: B0(8), A0(8) -> drain B0, keep A0 in flight
    asm volatile("s_waitcnt vmcnt(8)" ::: "memory");
    __builtin_amdgcn_s_barrier();

    #pragma unroll
    for (int i = 0; i < 8; ++i) {
        const int cur = i & 1, nxt = cur ^ 1;
        if (i < 7) {
            STAGE_B2(nxt, i + 1);                      // 8 DMA
            #pragma unroll
            for (int ks = 0; ks < 2; ++ks)
                #pragma unroll
                for (int nr = 0; nr < 4; ++nr)
                    af[nxt][ks][nr] = *(const bf16x8*)(
                        Ab + (size_t)(2 * i + 2 + ks) * 4096 + nr * 512);
        }

        // MFMA phase: 64 MFMA/wave; bc read 4-at-a-time to cap VGPR
        #pragma unroll
        for (int ks = 0; ks < 2; ++ks) {
            const char* Bsk = (const char*)Blds[cur] + ks * 16384;
            #pragma unroll
            for (int mch = 0; mch < 2; ++mch) {
                bf16x8 bc[4];
                #pragma unroll
                for (int j = 0; j < 4; ++j)
                    bc[j] = *(const bf16x8*)(Bsk +
                            (wn * 8 + mch * 4 + j) * 1024 + lane * 16);
                __builtin_amdgcn_s_setprio(1);
                #pragma unroll
                for (int j = 0; j < 4; ++j)
                    #pragma unroll
                    for (int nr = 0; nr < 4; ++nr)
                        acc[mch * 4 + j][nr] = __builtin_amdgcn_mfma_f32_16x16x32_bf16(
                            bc[j], af[cur][ks][nr], acc[mch * 4 + j][nr], 0, 0, 0);
                __builtin_amdgcn_s_setprio(0);
            }
        }

        // counted drain of B(i+1); keep A(i+1) (8) in flight
        if (i < 7) asm volatile("s_waitcnt vmcnt(8)" ::: "memory");
        else       asm volatile("s_waitcnt vmcnt(0)" ::: "memory");
        __builtin_amdgcn_s_barrier();
    }

    // ---- epilogue: cents lane-local; top-3 per row over 128 cents/wave ----
    float cnb[8][4];
    #pragma unroll
    for (int mc = 0; mc < 8; ++mc)
        #pragma unroll
        for (int reg = 0; reg < 4; ++reg)
            cnb[mc][reg] = cnorm[p0 + wn * 128 + mc * 16 + g * 4 + reg] + BIAS;

    #pragma unroll
    for (int nr = 0; nr < 4; ++nr) {
        unsigned int u0 = 0xFFFFFFFFu, u1 = 0xFFFFFFFFu, u2 = 0xFFFFFFFFu;
        #pragma unroll
        for (int mc = 0; mc < 8; ++mc)
            #pragma unroll
            for (int reg = 0; reg < 4; ++reg) {
                float v = fmaf(-2.f, acc[mc][nr][reg], cnb[mc][reg]);  // > 0
                unsigned int cl = (unsigned int)(wn * 128 + mc * 16 + g * 4 + reg);
                unsigned int u = (__float_as_uint(v) & 0xFFFFFF00u) | cl;
                TOP3_INS_U32(u0, u1, u2, u);
            }
        #pragma unroll
        for (int mask = 16; mask <= 32; mask <<= 1) {
            unsigned int o0 = (unsigned int)__shfl_xor((int)u0, mask);
            unsigned int o1 = (unsigned int)__shfl_xor((int)u1, mask);
            unsigned int o2 = (unsigned int)__shfl_xor((int)u2, mask);
            TOP3_INS_U32(u0, u1, u2, o0);
            TOP3_INS_U32(u0, u1, u2, o1);
            TOP3_INS_U32(u0, u1, u2, o2);
        }
        if (g == 0) {
            int rl = wm * 64 + nr * 16 + q;
            tops[wn][rl][0] = __uint_as_float(u0 & 0xFFFFFF00u) - BIAS;
            tops[wn][rl][1] = __uint_as_float(u1 & 0xFFFFFF00u) - BIAS;
            tops[wn][rl][2] = __uint_as_float(u2 & 0xFFFFFF00u) - BIAS;
        }
    }
    __syncthreads();

    if (tid < BM) {
        float a0v = tops[0][tid][0], a1v = tops[0][tid][1], a2v = tops[0][tid][2];
        TOP3_INSERT(a0v, a1v, a2v, tops[1][tid][0]);
        TOP3_INSERT(a0v, a1v, a2v, tops[1][tid][1]);
        TOP3_INSERT(a0v, a1v, a2v, tops[1][tid][2]);
        float* dst = wsTop + (size_t)(row0 + tid) * 12 + pblock * 3;
        dst[0] = a0v; dst[1] = a1v; dst[2] = a2v;
    }
}

// ---------------------------------------------------------------------------
// Final merge: fold 4 pblocks' top3, add row norm, sqrt + softmin, store.
// ---------------------------------------------------------------------------
__global__ __launch_bounds__(256) void merge_kernel(
        const float* __restrict__ wsTop, const float* __restrict__ fnorm,
        float* __restrict__ out) {
    int r = blockIdx.x * 256 + threadIdx.x;      // 25088 = 98*256 exact
    const float* p = wsTop + (size_t)r * 12;
    float t0 = p[0], t1 = p[1], t2 = p[2];
    #pragma unroll
    for (int pb = 1; pb < 4; ++pb) {
        TOP3_INSERT(t0, t1, t2, p[pb * 3 + 0]);
        TOP3_INSERT(t0, t1, t2, p[pb * 3 + 1]);
        TOP3_INSERT(t0, t1, t2, p[pb * 3 + 2]);
    }
    float fn = fnorm[r];
    float d0 = sqrtf(fmaxf(fn + t0, 0.f));
    float d1 = sqrtf(fmaxf(fn + t1, 0.f));
    float d2 = sqrtf(fmaxf(fn + t2, 0.f));
    float w0 = 1.f / (1.f + __expf(d0 - d1) + __expf(d0 - d2));
    out[r] = w0 * d0;
}

extern "C" void kernel_launch(void* const* d_in, const int* in_sizes, int n_in,
                              void* d_out, int out_size, void* d_ws, size_t ws_size,
                              hipStream_t stream) {
    (void)in_sizes; (void)n_in; (void)out_size; (void)ws_size;
    const float* embeds    = (const float*)d_in[0];   // [8,3136,512] fp32
    const float* centroids = (const float*)d_in[1];   // [1024,512]  fp32
    float* out = (float*)d_out;

    // ws layout (bytes):
    //   cnorm  @ 0         (4 KB)
    //   fnorm  @ 4096      (100,352 B)
    //   wsTop  @ 104448    (25088*4*3*4 = 1,204,224 B)  [row][pblock][3]
    //   EbT    @ 2512896   (25,690,112 B bf16, fragment-tiled)
    //   CbT    @ 28203008  (1,048,576 B bf16, fragment-tiled)  total ~27.9 MB
    char* ws = (char*)d_ws;
    float*          cnorm = (float*)(ws);
    float*          fnorm = (float*)(ws + 4096);
    float*          wsTop = (float*)(ws + 104448);
    unsigned short* EbT   = (unsigned short*)(ws + 2512896);
    unsigned short* CbT   = (unsigned short*)(ws + 28203008);

    tconv_fused_kernel<<<NROW / 32 + Pp / 32, 256, 0, stream>>>(
        embeds, centroids, EbT, CbT, fnorm, cnorm);
    mfma_topk_kernel<<<NMB_PAD * 4, 256, 0, stream>>>(EbT, CbT, cnorm, wsTop);
    merge_kernel<<<NROW / 256, 256, 0, stream>>>(wsTop, fnorm, out);
}

// Round 19
// 61.210 us; speedup vs baseline: 1.1318x; 1.1318x over previous
//
#include <hip/hip_runtime.h>
#include <math.h>

#define Cc 512
#define Pp 1024
#define NROW 25088      // B*N = 8*3136
#define BM 256          // rows per block (98 mtiles exactly)
#define BNP 256         // centroid cols per block (4 pblocks)
#define NMT 98          // 25088/256
#define BIAS 4096.f     // makes v = cn+BIAS-2dot strictly positive for packing

typedef short  bf16x8 __attribute__((ext_vector_type(8)));   // 8 bf16 = 4 VGPR
typedef float  f32x4  __attribute__((ext_vector_type(4)));
typedef unsigned short u16x8 __attribute__((ext_vector_type(8)));
typedef unsigned short u16x4 __attribute__((ext_vector_type(4)));

__device__ __forceinline__ unsigned short bf16_rne(float f) {
    unsigned int u = __float_as_uint(f);
    return (unsigned short)((u + 0x7fffu + ((u >> 16) & 1u)) >> 16);
}

#define TOP3_INSERT(t0, t1, t2, v)                                  \
    do {                                                            \
        float _n0 = fminf((t0), (v));                               \
        float _h0 = fmaxf((t0), (v));                               \
        float _n1 = fminf((t1), _h0);                               \
        float _h1 = fmaxf((t1), _h0);                               \
        float _n2 = fminf((t2), _h1);                               \
        (t0) = _n0; (t1) = _n1; (t2) = _n2;                         \
    } while (0)

#define TOP3_INS_U32(t0, t1, t2, v)                                 \
    do {                                                            \
        unsigned int _n0 = min((t0), (v));                          \
        unsigned int _h0 = max((t0), (v));                          \
        unsigned int _n1 = min((t1), _h0);                          \
        unsigned int _h1 = max((t1), _h0);                          \
        unsigned int _n2 = min((t2), _h1);                          \
        (t0) = _n0; (t1) = _n1; (t2) = _n2;                         \
    } while (0)

#define GLOAD_LDS16(gp, lp)                                             \
    __builtin_amdgcn_global_load_lds(                                   \
        (const __attribute__((address_space(1))) void*)(const void*)(gp),\
        (__attribute__((address_space(3))) void*)(void*)(lp), 16, 0, 0)

// ---------------------------------------------------------------------------
// Fused transpose-conv (proven): fp32 -> bf16 RNE, fragment-tiled, fused
// row squared-norm. Blocks 0..783 embeds, 784..815 centroids.
// Tile(m,kt,nrt) = m*128 + kt*kts + nrt (A: kts=8 per 128-row mblock;
// B: kts=64), 512 u16 each, lane l=g*16+q holds row q, k g*8..g*8+8.
// ---------------------------------------------------------------------------
__global__ __launch_bounds__(256) void tconv_fused_kernel(
        const float* __restrict__ embeds, const float* __restrict__ cents,
        unsigned short* __restrict__ EbT, unsigned short* __restrict__ CbT,
        float* __restrict__ fnorm, float* __restrict__ cnorm) {
    __shared__ unsigned short buf[32 * 512];   // 32 KB
    __shared__ float snorm[32 * 8];            // 1 KB

    const int bid = blockIdx.x;
    const bool isE = bid < (NROW / 32);
    const float*    src = isE ? embeds : cents;
    unsigned short* dst = isE ? EbT : CbT;
    float*          nrm = isE ? fnorm : cnorm;
    const int       lg  = isE ? 3 : 6;
    const int       kts = isE ? 8 : 64;
    const size_t R0 = (size_t)(isE ? bid : bid - NROW / 32) * 32;

    const int t = threadIdx.x;

    #pragma unroll
    for (int p = 0; p < 16; ++p) {
        int idx = p * 1024 + t * 4;
        float4 v = *(const float4*)(src + R0 * Cc + idx);
        u16x4 o;
        o[0] = bf16_rne(v.x); o[1] = bf16_rne(v.y);
        o[2] = bf16_rne(v.z); o[3] = bf16_rne(v.w);
        *(u16x4*)&buf[idx] = o;
    }
    __syncthreads();

    const int w = t >> 6, g = (t >> 4) & 3, q = t & 15, l = t & 63;
    const int rb = (int)(R0 >> 4);
    const int rowblk_base = rb + (rb >> lg) * (15 << lg);
    float fns = 0.f;
    #pragma unroll
    for (int p = 0; p < 8; ++p) {
        int cg  = p * 4 + w;
        int kt  = cg >> 1, nrt = cg & 1;
        int row = nrt * 16 + q;
        u16x8 ch = *(const u16x8*)&buf[row * 512 + kt * 32 + g * 8];
        #pragma unroll
        for (int i = 0; i < 8; ++i) {
            float x = __uint_as_float((unsigned int)(unsigned short)ch[i] << 16);
            fns = fmaf(x, x, fns);
        }
        size_t tile = (size_t)rowblk_base + (size_t)kt * kts + nrt;
        *(u16x8*)(dst + tile * 512 + l * 8) = ch;
    }
    snorm[((w & 1) * 16 + q) * 8 + (w >> 1) * 4 + g] = fns;
    __syncthreads();
    if (t < 32) {
        float s = 0.f;
        #pragma unroll
        for (int j = 0; j < 8; ++j) s += snorm[t * 8 + j];
        nrm[R0 + t] = s;
    }
}

// ---------------------------------------------------------------------------
// Main: 256x256 8-PHASE kernel (T3+T4 on fragment-tiled operands -> no
// swizzle needed; all LDS reads contiguous 1KB/wave = conflict-free).
// 512 thr = 8 waves (2 wm x 4 wn); wave tile = 128 rows x 64 cents;
// acc[mc 4][nr 8] = 128 AGPR. K loop: 8 K-tiles of BK=64, double-buffered
// 2x(32KB A + 32KB B) = 128KB LDS. Per K-tile: 8 phases
// {ds_read subtile (bc at ng==0 + 2 af); issue 2 DMA for tile i+1 (phases
// 0-3 only -> >=4-phase lead); raw s_barrier; 8 MFMA (setprio)}. Tile
// boundary only: vmcnt(0) + __syncthreads(). Compiler handles ds_read->
// MFMA waits (register deps). Swapped-operand MFMA + packed-u32 top-3.
// Grid: 392 = 98 mtiles x 4 pblocks, XCD-chunked (49 per XCD, pblocks of
// an mtile stay on one XCD).
// acc[mc][nr]: cent = p0+wn*64+mc*16+g*4+reg ; row = row0+wm*128+nr*16+q
// ---------------------------------------------------------------------------
__global__ __launch_bounds__(512) void mfma_topk_kernel(
        const unsigned short* __restrict__ EbT, const unsigned short* __restrict__ CbT,
        const float* __restrict__ cnorm, float* __restrict__ wsTop) {
    const int xcd = blockIdx.x & 7;
    const int t49 = blockIdx.x >> 3;          // 0..48
    const int gid = xcd * 49 + t49;           // 0..391
    const int mb  = gid >> 2;                 // 0..97
    const int pb  = gid & 3;                  // 0..3

    __shared__ unsigned short A2[2][16384];   // 2 x 32 KB
    __shared__ unsigned short B2[2][16384];   // 2 x 32 KB

    const int tid  = threadIdx.x;
    const int lane = tid & 63;
    const int w    = tid >> 6;
    const int wm   = w >> 2;       // 0..1  row half (128 rows)
    const int wn   = w & 3;        // 0..3  cent quarter (64 cents)
    const int g    = lane >> 4;    // 0..3
    const int q    = lane & 15;    // 0..15
    const int row0 = mb * BM;
    const int p0   = pb * BNP;
    const int m0   = 2 * mb;       // first 128-row mblock of this tile

    f32x4 acc[4][8];               // [mc][nr] = 128 AGPR
    #pragma unroll
    for (int mc = 0; mc < 4; ++mc)
        #pragma unroll
        for (int nr = 0; nr < 8; ++nr) acc[mc][nr] = (f32x4){0.f, 0.f, 0.f, 0.f};

    // stage chunk c (0..2047, 16B each) of K-tile i into buffer buf.
    // A: tl=c>>6 -> (mh=tl>>4, ks=(tl>>3)&1, nrt=tl&7); tile(m0+mh, 2i+ks, nrt)
    // B: tl -> (ks=tl>>4, ptl=tl&15); tile kt=2i+ks, pt=pb*16+ptl
    auto STAGE_CHUNK = [&](int buf, int i, int c) {
        int tl = c >> 6, ci = c & 63;
        GLOAD_LDS16(EbT + ((size_t)(m0 + (tl >> 4)) * 128
                           + (size_t)(2 * i + ((tl >> 3) & 1)) * 8 + (tl & 7)) * 512
                        + ci * 8,
                    (char*)A2[buf] + c * 16);
        GLOAD_LDS16(CbT + ((size_t)(2 * i + (tl >> 4)) * 64 + pb * 16 + (tl & 15)) * 512
                        + ci * 8,
                    (char*)B2[buf] + c * 16);
    };

    // prologue: stage K-tile 0 fully (4 chunks/thread = 8 DMA), drain, sync
    #pragma unroll
    for (int it = 0; it < 4; ++it) STAGE_CHUNK(0, 0, tid + it * 512);
    asm volatile("s_waitcnt vmcnt(0)" ::: "memory");
    __syncthreads();

    for (int i = 0; i < 8; ++i) {
        const int cur = i & 1;
        const char* Al = (const char*)A2[cur];
        const char* Bl = (const char*)B2[cur];
        bf16x8 bc[4];

        #pragma unroll
        for (int p = 0; p < 8; ++p) {
            const int ks = p >> 2, ng = p & 3;
            // ds_reads for this phase (compiler inserts lgkm waits pre-MFMA)
            if (ng == 0) {
                #pragma unroll
                for (int mc = 0; mc < 4; ++mc)
                    bc[mc] = *(const bf16x8*)(Bl +
                            (ks * 16 + wn * 4 + mc) * 1024 + lane * 16);
            }
            bf16x8 a0 = *(const bf16x8*)(Al +
                    ((wm * 2 + ks) * 8 + ng * 2 + 0) * 1024 + lane * 16);
            bf16x8 a1 = *(const bf16x8*)(Al +
                    ((wm * 2 + ks) * 8 + ng * 2 + 1) * 1024 + lane * 16);
            // staging for tile i+1: 2 DMA/thread in each of phases 0-3
            if (i < 7 && p < 4) STAGE_CHUNK(cur ^ 1, i + 1, tid + p * 512);

            __builtin_amdgcn_s_barrier();    // scheduling barrier (lockstep)
            __builtin_amdgcn_s_setprio(1);
            #pragma unroll
            for (int mc = 0; mc < 4; ++mc) {
                acc[mc][ng * 2 + 0] = __builtin_amdgcn_mfma_f32_16x16x32_bf16(
                    bc[mc], a0, acc[mc][ng * 2 + 0], 0, 0, 0);
                acc[mc][ng * 2 + 1] = __builtin_amdgcn_mfma_f32_16x16x32_bf16(
                    bc[mc], a1, acc[mc][ng * 2 + 1], 0, 0, 0);
            }
            __builtin_amdgcn_s_setprio(0);
        }
        // tile boundary: next tile's 8 DMAs (issued phases 0-3) must land;
        // __syncthreads fence also orders LDS reads vs next-tile overwrite
        if (i < 7) asm volatile("s_waitcnt vmcnt(0)" ::: "memory");
        __syncthreads();
    }

    // ---- epilogue: cents lane-local; top-3 per row over 64 cents/wave ----
    float cnb[4][4];
    #pragma unroll
    for (int mc = 0; mc < 4; ++mc)
        #pragma unroll
        for (int reg = 0; reg < 4; ++reg)
            cnb[mc][reg] = cnorm[p0 + wn * 64 + mc * 16 + g * 4 + reg] + BIAS;

    float* tops = (float*)B2;      // alias: [4][BM][3] floats = 12 KB (dead)

    #pragma unroll
    for (int nr = 0; nr < 8; ++nr) {
        unsigned int u0 = 0xFFFFFFFFu, u1 = 0xFFFFFFFFu, u2 = 0xFFFFFFFFu;
        #pragma unroll
        for (int mc = 0; mc < 4; ++mc)
            #pragma unroll
            for (int reg = 0; reg < 4; ++reg) {
                float v = fmaf(-2.f, acc[mc][nr][reg], cnb[mc][reg]);  // > 0
                unsigned int cl = (unsigned int)(wn * 64 + mc * 16 + g * 4 + reg);
                unsigned int u = (__float_as_uint(v) & 0xFFFFFF00u) | cl;
                TOP3_INS_U32(u0, u1, u2, u);
            }
        #pragma unroll
        for (int mask = 16; mask <= 32; mask <<= 1) {
            unsigned int o0 = (unsigned int)__shfl_xor((int)u0, mask);
            unsigned int o1 = (unsigned int)__shfl_xor((int)u1, mask);
            unsigned int o2 = (unsigned int)__shfl_xor((int)u2, mask);
            TOP3_INS_U32(u0, u1, u2, o0);
            TOP3_INS_U32(u0, u1, u2, o1);
            TOP3_INS_U32(u0, u1, u2, o2);
        }
        if (g == 0) {
            int rl = wm * 128 + nr * 16 + q;
            float* d = tops + ((size_t)wn * BM + rl) * 3;
            d[0] = __uint_as_float(u0 & 0xFFFFFF00u) - BIAS;
            d[1] = __uint_as_float(u1 & 0xFFFFFF00u) - BIAS;
            d[2] = __uint_as_float(u2 & 0xFFFFFF00u) - BIAS;
        }
    }
    __syncthreads();

    if (tid < BM) {
        const float* pp = tops + (size_t)tid * 3;
        float a0v = pp[0], a1v = pp[1], a2v = pp[2];
        #pragma unroll
        for (int x = 1; x < 4; ++x) {
            const float* px = tops + ((size_t)x * BM + tid) * 3;
            TOP3_INSERT(a0v, a1v, a2v, px[0]);
            TOP3_INSERT(a0v, a1v, a2v, px[1]);
            TOP3_INSERT(a0v, a1v, a2v, px[2]);
        }
        float* dst = wsTop + (size_t)(row0 + tid) * 12 + pb * 3;
        dst[0] = a0v; dst[1] = a1v; dst[2] = a2v;
    }
}

// ---------------------------------------------------------------------------
// Final merge: fold 4 pblocks' top3, add row norm, sqrt + softmin, store.
// ---------------------------------------------------------------------------
__global__ __launch_bounds__(256) void merge_kernel(
        const float* __restrict__ wsTop, const float* __restrict__ fnorm,
        float* __restrict__ out) {
    int r = blockIdx.x * 256 + threadIdx.x;      // 25088 = 98*256 exact
    const float* p = wsTop + (size_t)r * 12;
    float t0 = p[0], t1 = p[1], t2 = p[2];
    #pragma unroll
    for (int pb = 1; pb < 4; ++pb) {
        TOP3_INSERT(t0, t1, t2, p[pb * 3 + 0]);
        TOP3_INSERT(t0, t1, t2, p[pb * 3 + 1]);
        TOP3_INSERT(t0, t1, t2, p[pb * 3 + 2]);
    }
    float fn = fnorm[r];
    float d0 = sqrtf(fmaxf(fn + t0, 0.f));
    float d1 = sqrtf(fmaxf(fn + t1, 0.f));
    float d2 = sqrtf(fmaxf(fn + t2, 0.f));
    float w0 = 1.f / (1.f + __expf(d0 - d1) + __expf(d0 - d2));
    out[r] = w0 * d0;
}

extern "C" void kernel_launch(void* const* d_in, const int* in_sizes, int n_in,
                              void* d_out, int out_size, void* d_ws, size_t ws_size,
                              hipStream_t stream) {
    (void)in_sizes; (void)n_in; (void)out_size; (void)ws_size;
    const float* embeds    = (const float*)d_in[0];   // [8,3136,512] fp32
    const float* centroids = (const float*)d_in[1];   // [1024,512]  fp32
    float* out = (float*)d_out;

    // ws layout (bytes):
    //   cnorm  @ 0         (4 KB)
    //   fnorm  @ 4096      (100,352 B)
    //   wsTop  @ 104448    (25088*4*3*4 = 1,204,224 B)  [row][pblock][3]
    //   EbT    @ 2512896   (25,690,112 B bf16, fragment-tiled)
    //   CbT    @ 28203008  (1,048,576 B bf16, fragment-tiled)  total ~27.9 MB
    char* ws = (char*)d_ws;
    float*          cnorm = (float*)(ws);
    float*          fnorm = (float*)(ws + 4096);
    float*          wsTop = (float*)(ws + 104448);
    unsigned short* EbT   = (unsigned short*)(ws + 2512896);
    unsigned short* CbT   = (unsigned short*)(ws + 28203008);

    tconv_fused_kernel<<<NROW / 32 + Pp / 32, 256, 0, stream>>>(
        embeds, centroids, EbT, CbT, fnorm, cnorm);
    mfma_topk_kernel<<<NMT * 4, 512, 0, stream>>>(EbT, CbT, cnorm, wsTop);
    merge_kernel<<<NROW / 256, 256, 0, stream>>>(wsTop, fnorm, out);
}

// Round 20
// 51.212 us; speedup vs baseline: 1.3527x; 1.1952x over previous
//
#include <hip/hip_runtime.h>
#include <math.h>

#define Cc 512
#define Pp 1024
#define NROW 25088      // B*N = 8*3136
#define BM 128          // rows per block
#define BNP 128         // centroid cols per block (8 pblocks)
#define NMB 196         // real mblocks = 25088/128
#define NMB_PAD 200     // padded so mblocks group 8-per-XCD
#define BIAS 4096.f     // makes v = cn+BIAS-2dot strictly positive for packing

typedef short  bf16x8 __attribute__((ext_vector_type(8)));   // 8 bf16 = 4 VGPR
typedef float  f32x4  __attribute__((ext_vector_type(4)));
typedef unsigned short u16x8 __attribute__((ext_vector_type(8)));
typedef unsigned short u16x4 __attribute__((ext_vector_type(4)));

__device__ __forceinline__ unsigned short bf16_rne(float f) {
    unsigned int u = __float_as_uint(f);
    return (unsigned short)((u + 0x7fffu + ((u >> 16) & 1u)) >> 16);
}

// branch-free sorted insert (float), for cross-pblock merges
#define TOP3_INSERT(t0, t1, t2, v)                                  \
    do {                                                            \
        float _n0 = fminf((t0), (v));                               \
        float _h0 = fmaxf((t0), (v));                               \
        float _n1 = fminf((t1), _h0);                               \
        float _h1 = fmaxf((t1), _h0);                               \
        float _n2 = fminf((t2), _h1);                               \
        (t0) = _n0; (t1) = _n1; (t2) = _n2;                         \
    } while (0)

// branch-free sorted insert (packed u32: high-24 float bits | 8-bit col id)
#define TOP3_INS_U32(t0, t1, t2, v)                                 \
    do {                                                            \
        unsigned int _n0 = min((t0), (v));                          \
        unsigned int _h0 = max((t0), (v));                          \
        unsigned int _n1 = min((t1), _h0);                          \
        unsigned int _h1 = max((t1), _h0);                          \
        unsigned int _n2 = min((t2), _h1);                          \
        (t0) = _n0; (t1) = _n1; (t2) = _n2;                         \
    } while (0)

#define GLOAD_LDS16(gp, lp)                                             \
    __builtin_amdgcn_global_load_lds(                                   \
        (const __attribute__((address_space(1))) void*)(const void*)(gp),\
        (__attribute__((address_space(3))) void*)(void*)(lp), 16, 0, 0)

// ---------------------------------------------------------------------------
// Fused transpose-conv (proven): fp32 -> bf16 RNE, re-tiled into MFMA
// fragment order, fused row squared-norm. Blocks 0..783 embeds, 784..815
// centroids. Tile = 16 rows x 32 k = 64 chunks of 16B; chunk (g,q) at lane
// l = g*16+q. Tile id = rowblk_base + kt*kts + nrt,
// rowblk_base = rb + (rb>>lg)*(15<<lg).
// ---------------------------------------------------------------------------
__global__ __launch_bounds__(256) void tconv_fused_kernel(
        const float* __restrict__ embeds, const float* __restrict__ cents,
        unsigned short* __restrict__ EbT, unsigned short* __restrict__ CbT,
        float* __restrict__ fnorm, float* __restrict__ cnorm) {
    __shared__ unsigned short buf[32 * 512];   // 32 KB
    __shared__ float snorm[32 * 8];            // 1 KB

    const int bid = blockIdx.x;
    const bool isE = bid < (NROW / 32);
    const float*    src = isE ? embeds : cents;
    unsigned short* dst = isE ? EbT : CbT;
    float*          nrm = isE ? fnorm : cnorm;
    const int       lg  = isE ? 3 : 6;
    const int       kts = isE ? 8 : 64;
    const size_t R0 = (size_t)(isE ? bid : bid - NROW / 32) * 32;

    const int t = threadIdx.x;

    #pragma unroll
    for (int p = 0; p < 16; ++p) {
        int idx = p * 1024 + t * 4;
        float4 v = *(const float4*)(src + R0 * Cc + idx);
        u16x4 o;
        o[0] = bf16_rne(v.x); o[1] = bf16_rne(v.y);
        o[2] = bf16_rne(v.z); o[3] = bf16_rne(v.w);
        *(u16x4*)&buf[idx] = o;
    }
    __syncthreads();

    const int w = t >> 6, g = (t >> 4) & 3, q = t & 15, l = t & 63;
    const int rb = (int)(R0 >> 4);
    const int rowblk_base = rb + (rb >> lg) * (15 << lg);
    float fns = 0.f;
    #pragma unroll
    for (int p = 0; p < 8; ++p) {
        int cg  = p * 4 + w;              // tile-local group 0..31
        int kt  = cg >> 1, nrt = cg & 1;
        int row = nrt * 16 + q;
        u16x8 ch = *(const u16x8*)&buf[row * 512 + kt * 32 + g * 8];
        #pragma unroll
        for (int i = 0; i < 8; ++i) {
            float x = __uint_as_float((unsigned int)(unsigned short)ch[i] << 16);
            fns = fmaf(x, x, fns);
        }
        size_t tile = (size_t)rowblk_base + (size_t)kt * kts + nrt;
        *(u16x8*)(dst + tile * 512 + l * 8) = ch;
    }
    snorm[((w & 1) * 16 + q) * 8 + (w >> 1) * 4 + g] = fns;
    __syncthreads();
    if (t < 32) {
        float s = 0.f;
        #pragma unroll
        for (int j = 0; j < 8; ++j) s += snorm[t * 8 + j];
        nrm[R0 + t] = s;
    }
}

// ---------------------------------------------------------------------------
// Main (best measured structure, R12/R15): split-pipe 128x128 MFMA tile,
// TWO k-steps per barrier (32 MFMA/wave between barriers). A fragments
// direct global->VGPR prefetched 2 k-steps ahead (compiler-counted reg
// waits). B double-buffered 2x16KB via gload_lds (4 DMA/thread per iter);
// counted vmcnt(8) per step drains next iter's B, keeps the 8 A loads in
// flight (never 0 until tail). Fragment-ordered reads: contiguous 1KB/wave
// => conflict-free, no swizzle. Swapped-operand MFMA (cents lane-local in
// C) + packed-u32 top-3. Register footprint ~68 VGPR + 64 AGPR;
// __launch_bounds__(256,3) is the max this admits (R14: capping higher
// spills to scratch; R16: shrinking af costs latency; R18: widening BNP
// costs occupancy; R19: 8-phase 256^2 loses to grid tail). This structure
// is the measured optimum of the explored space.
// Grid: 1600 blocks (200 padded mblocks x 8 pblocks), 256 thr = 4 waves 2x2.
// acc[mc][nr]: cent = p0+wn*64+mc*16+g*4+reg ; row = row0+wm*64+nr*16+q
// ---------------------------------------------------------------------------
__global__ __launch_bounds__(256, 3) void mfma_topk_kernel(
        const unsigned short* __restrict__ EbT, const unsigned short* __restrict__ CbT,
        const float* __restrict__ cnorm, float* __restrict__ wsTop) {
    const int xcd = blockIdx.x & 7;
    const int t8  = blockIdx.x >> 3;          // 0..199
    const int mblock = ((t8 >> 3) << 3) | xcd;
    const int pblock = t8 & 7;
    if (mblock >= NMB) return;                // uniform early-exit

    __shared__ unsigned short Blds[2][8192];  // 2 x 16 KB (2 k-panels each)
    __shared__ float tops[2][BM][3];          // 3 KB

    const int tid  = threadIdx.x;
    const int lane = tid & 63;
    const int w    = tid >> 6;
    const int wm   = w >> 1;       // 0..1 row half
    const int wn   = w & 1;        // 0..1 cent half
    const int g    = lane >> 4;    // 0..3
    const int q    = lane & 15;    // 0..15
    const int row0 = mblock * BM;
    const int p0   = pblock * BNP;

    f32x4 acc[4][4];               // [mc][nr] = 64 AGPR
    #pragma unroll
    for (int mc = 0; mc < 4; ++mc)
        #pragma unroll
        for (int nr = 0; nr < 4; ++nr) acc[mc][nr] = (f32x4){0.f, 0.f, 0.f, 0.f};

    // A fragment base (u16): tile=512 u16, tiles [mblock][kt 16][nrt 8]
    const unsigned short* Ab = EbT + ((size_t)mblock * 128 + wm * 4) * 512 + lane * 8;
    // B: tiles [kt 16][ptile 64]; this block's 8 tiles per kt are contiguous
    const unsigned short* Bg = CbT + (size_t)pblock * 8 * 512;

    // stage TWO k-panels (kt = 2i, 2i+1) into buffer buf: 4 DMA instrs/thread
    auto STAGE_B2 = [&](int buf, int i) {
        #pragma unroll
        for (int ks = 0; ks < 2; ++ks) {
            const unsigned short* src = Bg + (size_t)(2 * i + ks) * 32768;
            #pragma unroll
            for (int it = 0; it < 2; ++it) {
                int c = tid + it * 256;
                GLOAD_LDS16(src + c * 8, (char*)Blds[buf] + ks * 8192 + c * 16);
            }
        }
    };

    bf16x8 af[2][2][4];            // [buf][ks][nr] = 64 VGPR
    STAGE_B2(0, 0);                // B iter0 (kt 0,1): 4 DMA
    #pragma unroll
    for (int ks = 0; ks < 2; ++ks)
        #pragma unroll
        for (int nr = 0; nr < 4; ++nr)
            af[0][ks][nr] = *(const bf16x8*)(Ab + (size_t)ks * 4096 + nr * 512);
    // in flight: B0(4 oldest) + A0(8) -> drain B0, keep A0
    asm volatile("s_waitcnt vmcnt(8)" ::: "memory");
    __builtin_amdgcn_s_barrier();

    #pragma unroll
    for (int i = 0; i < 8; ++i) {
        const int cur = i & 1, nxt = cur ^ 1;
        if (i < 7) {
            STAGE_B2(nxt, i + 1);                      // 4 DMA
            #pragma unroll
            for (int ks = 0; ks < 2; ++ks)
                #pragma unroll
                for (int nr = 0; nr < 4; ++nr)
                    af[nxt][ks][nr] = *(const bf16x8*)(
                        Ab + (size_t)(2 * i + 2 + ks) * 4096 + nr * 512);
        }

        #pragma unroll
        for (int ks = 0; ks < 2; ++ks) {
            const char* Bsk = (const char*)Blds[cur] + ks * 8192;
            bf16x8 bc[4];
            #pragma unroll
            for (int mc = 0; mc < 4; ++mc)
                bc[mc] = *(const bf16x8*)(Bsk + (wn * 4 + mc) * 1024 + lane * 16);
            __builtin_amdgcn_s_setprio(1);
            #pragma unroll
            for (int mc = 0; mc < 4; ++mc)
                #pragma unroll
                for (int nr = 0; nr < 4; ++nr)
                    acc[mc][nr] = __builtin_amdgcn_mfma_f32_16x16x32_bf16(
                        bc[mc], af[cur][ks][nr], acc[mc][nr], 0, 0, 0);
            __builtin_amdgcn_s_setprio(0);
        }

        // drain next iter's B(4); keep next iter's A(8) in flight
        if (i < 7) asm volatile("s_waitcnt vmcnt(8)" ::: "memory");
        else       asm volatile("s_waitcnt vmcnt(0)" ::: "memory");
        __builtin_amdgcn_s_barrier();
    }

    // ---- epilogue: cents lane-local; top-3 per row over 64 cents/wave ----
    float cnb[4][4];
    #pragma unroll
    for (int mc = 0; mc < 4; ++mc)
        #pragma unroll
        for (int reg = 0; reg < 4; ++reg)
            cnb[mc][reg] = cnorm[p0 + wn * 64 + mc * 16 + g * 4 + reg] + BIAS;

    #pragma unroll
    for (int nr = 0; nr < 4; ++nr) {
        unsigned int u0 = 0xFFFFFFFFu, u1 = 0xFFFFFFFFu, u2 = 0xFFFFFFFFu;
        #pragma unroll
        for (int mc = 0; mc < 4; ++mc)
            #pragma unroll
            for (int reg = 0; reg < 4; ++reg) {
                float v = fmaf(-2.f, acc[mc][nr][reg], cnb[mc][reg]);  // > 0
                unsigned int cl = (unsigned int)(wn * 64 + mc * 16 + g * 4 + reg);
                unsigned int u = (__float_as_uint(v) & 0xFFFFFF00u) | cl;
                TOP3_INS_U32(u0, u1, u2, u);
            }
        #pragma unroll
        for (int mask = 16; mask <= 32; mask <<= 1) {
            unsigned int o0 = (unsigned int)__shfl_xor((int)u0, mask);
            unsigned int o1 = (unsigned int)__shfl_xor((int)u1, mask);
            unsigned int o2 = (unsigned int)__shfl_xor((int)u2, mask);
            TOP3_INS_U32(u0, u1, u2, o0);
            TOP3_INS_U32(u0, u1, u2, o1);
            TOP3_INS_U32(u0, u1, u2, o2);
        }
        if (g == 0) {
            int rl = wm * 64 + nr * 16 + q;
            tops[wn][rl][0] = __uint_as_float(u0 & 0xFFFFFF00u) - BIAS;
            tops[wn][rl][1] = __uint_as_float(u1 & 0xFFFFFF00u) - BIAS;
            tops[wn][rl][2] = __uint_as_float(u2 & 0xFFFFFF00u) - BIAS;
        }
    }
    __syncthreads();

    if (tid < BM) {
        float a0v = tops[0][tid][0], a1v = tops[0][tid][1], a2v = tops[0][tid][2];
        TOP3_INSERT(a0v, a1v, a2v, tops[1][tid][0]);
        TOP3_INSERT(a0v, a1v, a2v, tops[1][tid][1]);
        TOP3_INSERT(a0v, a1v, a2v, tops[1][tid][2]);
        float* dst = wsTop + (size_t)(row0 + tid) * 24 + pblock * 3;
        dst[0] = a0v; dst[1] = a1v; dst[2] = a2v;
    }
}

// ---------------------------------------------------------------------------
// Final merge: fold 8 pblocks' top3, add row norm, sqrt + softmin, store.
// ---------------------------------------------------------------------------
__global__ __launch_bounds__(256) void merge_kernel(
        const float* __restrict__ wsTop, const float* __restrict__ fnorm,
        float* __restrict__ out) {
    int r = blockIdx.x * 256 + threadIdx.x;      // 25088 = 98*256 exact
    const float* p = wsTop + (size_t)r * 24;
    float t0 = p[0], t1 = p[1], t2 = p[2];
    #pragma unroll
    for (int pb = 1; pb < 8; ++pb) {
        TOP3_INSERT(t0, t1, t2, p[pb * 3 + 0]);
        TOP3_INSERT(t0, t1, t2, p[pb * 3 + 1]);
        TOP3_INSERT(t0, t1, t2, p[pb * 3 + 2]);
    }
    float fn = fnorm[r];
    float d0 = sqrtf(fmaxf(fn + t0, 0.f));
    float d1 = sqrtf(fmaxf(fn + t1, 0.f));
    float d2 = sqrtf(fmaxf(fn + t2, 0.f));
    float w0 = 1.f / (1.f + __expf(d0 - d1) + __expf(d0 - d2));
    out[r] = w0 * d0;
}

extern "C" void kernel_launch(void* const* d_in, const int* in_sizes, int n_in,
                              void* d_out, int out_size, void* d_ws, size_t ws_size,
                              hipStream_t stream) {
    (void)in_sizes; (void)n_in; (void)out_size; (void)ws_size;
    const float* embeds    = (const float*)d_in[0];   // [8,3136,512] fp32
    const float* centroids = (const float*)d_in[1];   // [1024,512]  fp32
    float* out = (float*)d_out;

    // ws layout (bytes):
    //   cnorm  @ 0         (4 KB)
    //   fnorm  @ 4096      (100,352 B)
    //   wsTop  @ 104448    (25088*8*3*4 = 2,408,448 B)  [row][pblock][3]
    //   EbT    @ 2512896   (25,690,112 B bf16, fragment-tiled)
    //   CbT    @ 28203008  (1,048,576 B bf16, fragment-tiled)  total ~27.9 MB
    char* ws = (char*)d_ws;
    float*          cnorm = (float*)(ws);
    float*          fnorm = (float*)(ws + 4096);
    float*          wsTop = (float*)(ws + 104448);
    unsigned short* EbT   = (unsigned short*)(ws + 2512896);
    unsigned short* CbT   = (unsigned short*)(ws + 28203008);

    tconv_fused_kernel<<<NROW / 32 + Pp / 32, 256, 0, stream>>>(
        embeds, centroids, EbT, CbT, fnorm, cnorm);
    mfma_topk_kernel<<<NMB_PAD * 8, 256, 0, stream>>>(EbT, CbT, cnorm, wsTop);
    merge_kernel<<<NROW / 256, 256, 0, stream>>>(wsTop, fnorm, out);
}